// Round 2
// baseline (127.023 us; speedup 1.0000x reference)
//
#include <hip/hip_runtime.h>
#include <stdint.h>

typedef __bf16 bf16;
typedef __bf16 bf16x4 __attribute__((ext_vector_type(4)));
typedef __bf16 bf16x8 __attribute__((ext_vector_type(8)));
typedef float f32x16 __attribute__((ext_vector_type(16)));

#define BDIM 8192
#define DDIM 128
#define LDW 68   // LDS row stride in bf16 (64 + 4 pad -> 2-way bank aliasing = free)

__device__ __forceinline__ uint32_t f2bf1(float f) {
    uint32_t u = __float_as_uint(f);
    return (u + 0x7FFFu + ((u >> 16) & 1u)) >> 16;   // RNE
}

// fp32 [8192,128] -> packed bf16, fp32 row sum-of-squares; block(0,0) zeroes out.
__global__ __launch_bounds__(256) void prep_kernel(const float* __restrict__ out_f,
                                                   const float* __restrict__ tgt_f,
                                                   uint32_t* __restrict__ ab,
                                                   float* __restrict__ xxyy,
                                                   float* __restrict__ out) {
    if (blockIdx.x == 0 && blockIdx.y == 0 && threadIdx.x == 0) out[0] = 0.0f;

    const float* src = blockIdx.y ? tgt_f : out_f;
    uint32_t* dst = ab + (size_t)blockIdx.y * (BDIM * DDIM / 2);
    float* nrm = xxyy + (size_t)blockIdx.y * BDIM;

    int wid = threadIdx.x >> 6;
    int lane = threadIdx.x & 63;
    int row = blockIdx.x * 4 + wid;

    const float2* s = (const float2*)(src + (size_t)row * DDIM);
    float2 v = s[lane];
    dst[row * (DDIM / 2) + lane] = f2bf1(v.x) | (f2bf1(v.y) << 16);

    float sq = v.x * v.x + v.y * v.y;
    #pragma unroll
    for (int off = 32; off > 0; off >>= 1) sq += __shfl_down(sq, off);
    if (lane == 0) nrm[row] = sq;
}

// 128x128 tile per block; C = A * B^T via mfma 32x32x16 bf16;
// fused d = sqrt(max(xx+yy-2c,0)); diag fixed in a rare second pass;
// block partial atomically accumulated into out (pre-scaled).
__global__ __launch_bounds__(256) void dist_kernel(const uint32_t* __restrict__ Ag,
                                                   const uint32_t* __restrict__ Bg,
                                                   const float* __restrict__ xxg,
                                                   const float* __restrict__ yyg,
                                                   float* __restrict__ out) {
    __shared__ bf16 Al[128 * LDW];
    __shared__ bf16 Bl[128 * LDW];
    __shared__ float xxl[128];
    __shared__ float yyl[128];
    __shared__ float wsum[4];

    const int tid = threadIdx.x;
    const int lane = tid & 63;
    const int wid = tid >> 6;
    const int wr = wid >> 1, wc = wid & 1;      // 2x2 wave grid, each wave 64x64
    const int bx = blockIdx.x, by = blockIdx.y;

    if (tid < 128) xxl[tid] = xxg[bx * 128 + tid];
    else           yyl[tid - 128] = yyg[by * 128 + (tid - 128)];

    const uint2* Ga = (const uint2*)Ag + (size_t)bx * 128 * 32;  // 32 uint2/row
    const uint2* Gb = (const uint2*)Bg + (size_t)by * 128 * 32;

    const int sseg = tid & 15;        // constant: (tid + i*256) & 15
    const int r0 = tid >> 4;          // row advances by 16 per i

    f32x16 acc[2][2] = {};

    #pragma unroll
    for (int ch = 0; ch < 2; ++ch) {            // two K-chunks of 64
        if (ch) __syncthreads();
        const int ck = ch * 16;
        #pragma unroll
        for (int i = 0; i < 8; ++i) {
            int r = r0 + i * 16;
            uint2 va = Ga[r * 32 + ck + sseg];
            uint2 vb = Gb[r * 32 + ck + sseg];
            *(uint2*)&Al[r * LDW + sseg * 4] = va;
            *(uint2*)&Bl[r * LDW + sseg * 4] = vb;
        }
        __syncthreads();

        #pragma unroll
        for (int k0 = 0; k0 < 64; k0 += 16) {
            const int kk = k0 + ((lane >> 5) << 3);
            bf16x8 af[2], bfr[2];
            #pragma unroll
            for (int t = 0; t < 2; ++t) {
                int am = wr * 64 + t * 32 + (lane & 31);
                bf16x4 lo = *(const bf16x4*)&Al[am * LDW + kk];
                bf16x4 hi = *(const bf16x4*)&Al[am * LDW + kk + 4];
                af[t] = __builtin_shufflevector(lo, hi, 0, 1, 2, 3, 4, 5, 6, 7);
                int bn = wc * 64 + t * 32 + (lane & 31);
                bf16x4 lo2 = *(const bf16x4*)&Bl[bn * LDW + kk];
                bf16x4 hi2 = *(const bf16x4*)&Bl[bn * LDW + kk + 4];
                bfr[t] = __builtin_shufflevector(lo2, hi2, 0, 1, 2, 3, 4, 5, 6, 7);
            }
            acc[0][0] = __builtin_amdgcn_mfma_f32_32x32x16_bf16(af[0], bfr[0], acc[0][0], 0, 0, 0);
            acc[0][1] = __builtin_amdgcn_mfma_f32_32x32x16_bf16(af[0], bfr[1], acc[0][1], 0, 0, 0);
            acc[1][0] = __builtin_amdgcn_mfma_f32_32x32x16_bf16(af[1], bfr[0], acc[1][0], 0, 0, 0);
            acc[1][1] = __builtin_amdgcn_mfma_f32_32x32x16_bf16(af[1], bfr[1], acc[1][1], 0, 0, 0);
        }
    }

    // Epilogue: s += sqrt(max(xx+yy-2c, 0)) for every element (fast sqrt).
    float s = 0.0f;
    #pragma unroll
    for (int tr = 0; tr < 2; ++tr) {
        float xv[16];
        #pragma unroll
        for (int r = 0; r < 16; ++r) {
            int ml = wr * 64 + tr * 32 + (r & 3) + 8 * (r >> 2) + 4 * (lane >> 5);
            xv[r] = xxl[ml];
        }
        #pragma unroll
        for (int tc = 0; tc < 2; ++tc) {
            float yv = yyl[wc * 64 + tc * 32 + (lane & 31)];
            #pragma unroll
            for (int r = 0; r < 16; ++r) {
                float d2 = fmaf(-2.0f, acc[tr][tc][r], xv[r] + yv);
                s += __builtin_amdgcn_sqrtf(fmaxf(d2, 0.0f));
            }
        }
    }

    // Diagonal correction: only 64 of 4096 blocks, only waves with wr==wc.
    if (bx == by && wr == wc) {
        const int col = lane & 31;
        #pragma unroll
        for (int t = 0; t < 2; ++t) {
            #pragma unroll
            for (int r = 0; r < 16; ++r) {
                int row = (r & 3) + 8 * (r >> 2) + 4 * (lane >> 5);
                if (row == col) {
                    int idx = wr * 64 + t * 32 + row;
                    float d2 = fmaf(-2.0f, acc[t][t][r], xxl[idx] + yyl[idx]);
                    s -= 2.0f * __builtin_amdgcn_sqrtf(fmaxf(d2, 0.0f));
                }
            }
        }
    }

    #pragma unroll
    for (int off = 32; off > 0; off >>= 1) s += __shfl_down(s, off);
    if (lane == 0) wsum[wid] = s;
    __syncthreads();
    if (tid == 0)
        atomicAdd(out, (wsum[0] + wsum[1] + wsum[2] + wsum[3]) * (0.1f / 8192.0f));
}

extern "C" void kernel_launch(void* const* d_in, const int* in_sizes, int n_in,
                              void* d_out, int out_size, void* d_ws, size_t ws_size,
                              hipStream_t stream) {
    const float* output = (const float*)d_in[0];
    const float* target = (const float*)d_in[1];

    uint8_t* ws = (uint8_t*)d_ws;
    uint32_t* ab   = (uint32_t*)ws;                         // A bf16 (2MB) + B bf16 (2MB)
    float*    xxyy = (float*)(ws + 4u * 1024u * 1024u);     // xx (32KB) + yy (32KB)

    prep_kernel<<<dim3(2048, 2), 256, 0, stream>>>(output, target, ab, xxyy, (float*)d_out);
    dist_kernel<<<dim3(64, 64), 256, 0, stream>>>(ab, ab + (BDIM * DDIM / 2),
                                                  xxyy, xxyy + BDIM, (float*)d_out);
}

// Round 3
// 95.023 us; speedup vs baseline: 1.3368x; 1.3368x over previous
//
#include <hip/hip_runtime.h>
#include <stdint.h>

typedef __bf16 bf16;
typedef __bf16 bf16x8 __attribute__((ext_vector_type(8)));
typedef float f32x16 __attribute__((ext_vector_type(16)));

#define BDIM 8192
#define DDIM 128

__device__ __forceinline__ uint32_t f2bf1(float f) {
    uint32_t u = __float_as_uint(f);
    return (u + 0x7FFFu + ((u >> 16) & 1u)) >> 16;   // RNE
}

// Async global->LDS, 16B per lane. LDS dest = wave-uniform base + lane*16.
__device__ __forceinline__ void gload16(const void* g, void* l) {
    __builtin_amdgcn_global_load_lds(
        (const __attribute__((address_space(1))) uint32_t*)g,
        (__attribute__((address_space(3))) uint32_t*)l,
        16, 0, 0);
}

// fp32 [8192,128] -> packed bf16, fp32 row sum-of-squares.
__global__ __launch_bounds__(256) void prep_kernel(const float* __restrict__ out_f,
                                                   const float* __restrict__ tgt_f,
                                                   uint32_t* __restrict__ ab,
                                                   float* __restrict__ xxyy) {
    const float* src = blockIdx.y ? tgt_f : out_f;
    uint32_t* dst = ab + (size_t)blockIdx.y * (BDIM * DDIM / 2);
    float* nrm = xxyy + (size_t)blockIdx.y * BDIM;

    int wid = threadIdx.x >> 6;
    int lane = threadIdx.x & 63;
    int row = blockIdx.x * 4 + wid;

    const float2* s = (const float2*)(src + (size_t)row * DDIM);
    float2 v = s[lane];
    dst[row * (DDIM / 2) + lane] = f2bf1(v.x) | (f2bf1(v.y) << 16);

    float sq = v.x * v.x + v.y * v.y;
    #pragma unroll
    for (int off = 32; off > 0; off >>= 1) sq += __shfl_down(sq, off);
    if (lane == 0) nrm[row] = sq;
}

// 128x128 tile per block; C = A * B^T via mfma 32x32x16 bf16.
// LDS: dense XOR-swizzled layout, staged with global_load_lds(16B).
//   slot(r, g) = r*8 + (g ^ (r&7))   (16B slots; r = row 0..127, g = k-group 0..7)
// Fragment read for row m, k-group g: single ds_read_b128 at slot(m, g) —
// conflict-free bank pattern (each 8 consecutive lanes cover all 32 banks).
__global__ __launch_bounds__(256) void dist_kernel(const uint32_t* __restrict__ Ag,
                                                   const uint32_t* __restrict__ Bg,
                                                   const float* __restrict__ xxg,
                                                   const float* __restrict__ yyg,
                                                   float* __restrict__ partials) {
    __shared__ bf16 Al[128 * 64];   // 16 KB per chunk (K=64), reused across chunks
    __shared__ bf16 Bl[128 * 64];
    __shared__ float xxl[128];
    __shared__ float yyl[128];
    __shared__ float wsum[4];

    const int tid = threadIdx.x;
    const int lane = tid & 63;
    const int wid = tid >> 6;
    const int wr = wid >> 1, wc = wid & 1;      // 2x2 wave grid, each wave 64x64
    const int bx = blockIdx.x, by = blockIdx.y;

    if (tid < 128) xxl[tid] = xxg[bx * 128 + tid];
    else           yyl[tid - 128] = yyg[by * 128 + (tid - 128)];

    // Staging constants (invariant per thread):
    //   slot S = i*256 + tid; r = i*32 + (tid>>3); g' = tid&7; g = g' ^ (r&7)
    //   (r&7) == (tid>>3)&7 since i*32 ≡ 0 mod 8  ->  g is loop-invariant.
    const int rl = tid >> 3;
    const int g  = (tid & 7) ^ (rl & 7);
    const uint8_t* Abase = (const uint8_t*)Ag + ((size_t)bx * 128) * 256  // 256 B/row
                         + rl * 256 + g * 16;
    const uint8_t* Bbase = (const uint8_t*)Bg + ((size_t)by * 128) * 256
                         + rl * 256 + g * 16;
    uint8_t* la = (uint8_t*)Al + tid * 16;
    uint8_t* lb = (uint8_t*)Bl + tid * 16;

    const int lm = lane & 31;                   // fragment row within 32
    const int fh = lane >> 5;                   // k-half

    f32x16 acc[2][2] = {};

    #pragma unroll
    for (int ch = 0; ch < 2; ++ch) {            // two K-chunks of 64
        if (ch) __syncthreads();                // previous compute done
        const uint8_t* ga = Abase + ch * 128;   // chunk = 128 B within the row
        const uint8_t* gb = Bbase + ch * 128;
        #pragma unroll
        for (int i = 0; i < 4; ++i) {           // i advances r by 32 -> +8192 B global
            gload16(ga + i * 8192, la + i * 4096);
            gload16(gb + i * 8192, lb + i * 4096);
        }
        __syncthreads();                        // drains vmcnt -> LDS visible

        #pragma unroll
        for (int k0 = 0; k0 < 64; k0 += 16) {
            const int gf = (k0 >> 3) + fh;      // k-group 0..7
            bf16x8 af[2], bfr[2];
            #pragma unroll
            for (int t = 0; t < 2; ++t) {
                int am = wr * 64 + t * 32 + lm;
                af[t]  = *(const bf16x8*)&Al[(am * 8 + (gf ^ (am & 7))) * 8];
                int bn = wc * 64 + t * 32 + lm;
                bfr[t] = *(const bf16x8*)&Bl[(bn * 8 + (gf ^ (bn & 7))) * 8];
            }
            acc[0][0] = __builtin_amdgcn_mfma_f32_32x32x16_bf16(af[0], bfr[0], acc[0][0], 0, 0, 0);
            acc[0][1] = __builtin_amdgcn_mfma_f32_32x32x16_bf16(af[0], bfr[1], acc[0][1], 0, 0, 0);
            acc[1][0] = __builtin_amdgcn_mfma_f32_32x32x16_bf16(af[1], bfr[0], acc[1][0], 0, 0, 0);
            acc[1][1] = __builtin_amdgcn_mfma_f32_32x32x16_bf16(af[1], bfr[1], acc[1][1], 0, 0, 0);
        }
    }

    // Epilogue: s += sqrt(max(xx+yy-2c, 0)) for every element (fast sqrt).
    float s = 0.0f;
    #pragma unroll
    for (int tr = 0; tr < 2; ++tr) {
        float xv[16];
        #pragma unroll
        for (int r = 0; r < 16; ++r) {
            int ml = wr * 64 + tr * 32 + (r & 3) + 8 * (r >> 2) + 4 * fh;
            xv[r] = xxl[ml];
        }
        #pragma unroll
        for (int tc = 0; tc < 2; ++tc) {
            float yv = yyl[wc * 64 + tc * 32 + lm];
            #pragma unroll
            for (int r = 0; r < 16; ++r) {
                float d2 = fmaf(-2.0f, acc[tr][tc][r], xv[r] + yv);
                s += __builtin_amdgcn_sqrtf(fmaxf(d2, 0.0f));
            }
        }
    }

    // Diagonal correction: only 64 of 4096 blocks, only waves with wr==wc.
    if (bx == by && wr == wc) {
        #pragma unroll
        for (int t = 0; t < 2; ++t) {
            #pragma unroll
            for (int r = 0; r < 16; ++r) {
                int row = (r & 3) + 8 * (r >> 2) + 4 * fh;
                if (row == lm) {
                    int idx = wr * 64 + t * 32 + row;
                    float d2 = fmaf(-2.0f, acc[t][t][r], xxl[idx] + yyl[idx]);
                    s -= 2.0f * __builtin_amdgcn_sqrtf(fmaxf(d2, 0.0f));
                }
            }
        }
    }

    #pragma unroll
    for (int off = 32; off > 0; off >>= 1) s += __shfl_down(s, off);
    if (lane == 0) wsum[wid] = s;
    __syncthreads();
    if (tid == 0) partials[by * 64 + bx] = wsum[0] + wsum[1] + wsum[2] + wsum[3];
}

__global__ __launch_bounds__(256) void reduce_kernel(const float* __restrict__ partials,
                                                     float* __restrict__ out) {
    __shared__ float wsum[4];
    float s = 0.0f;
    for (int i = threadIdx.x; i < 4096; i += 256) s += partials[i];
    #pragma unroll
    for (int off = 32; off > 0; off >>= 1) s += __shfl_down(s, off);
    int lane = threadIdx.x & 63, wid = threadIdx.x >> 6;
    if (lane == 0) wsum[wid] = s;
    __syncthreads();
    if (threadIdx.x == 0)
        out[0] = (wsum[0] + wsum[1] + wsum[2] + wsum[3]) * (0.1f / 8192.0f);
}

extern "C" void kernel_launch(void* const* d_in, const int* in_sizes, int n_in,
                              void* d_out, int out_size, void* d_ws, size_t ws_size,
                              hipStream_t stream) {
    const float* output = (const float*)d_in[0];
    const float* target = (const float*)d_in[1];

    uint8_t* ws = (uint8_t*)d_ws;
    uint32_t* ab      = (uint32_t*)ws;                                   // A bf16 (2MB) + B bf16 (2MB)
    float*    xxyy    = (float*)(ws + 4u * 1024u * 1024u);               // xx (32KB) + yy (32KB)
    float*    partial = (float*)(ws + 4u * 1024u * 1024u + 64u * 1024u); // 4096 floats

    prep_kernel<<<dim3(2048, 2), 256, 0, stream>>>(output, target, ab, xxyy);
    dist_kernel<<<dim3(64, 64), 256, 0, stream>>>(ab, ab + (BDIM * DDIM / 2),
                                                  xxyy, xxyy + BDIM, partial);
    reduce_kernel<<<1, 256, 0, stream>>>(partial, (float*)d_out);
}

// Round 4
// 94.471 us; speedup vs baseline: 1.3446x; 1.0058x over previous
//
#include <hip/hip_runtime.h>
#include <stdint.h>

typedef __bf16 bf16;
typedef __bf16 bf16x8 __attribute__((ext_vector_type(8)));
typedef float f32x16 __attribute__((ext_vector_type(16)));

#define BDIM 8192
#define DDIM 128

__device__ __forceinline__ uint32_t f2bf1(float f) {
    uint32_t u = __float_as_uint(f);
    return (u + 0x7FFFu + ((u >> 16) & 1u)) >> 16;   // RNE
}

// Async global->LDS, 16B per lane. LDS dest = wave-uniform base + lane*16.
__device__ __forceinline__ void gload16(const void* g, void* l) {
    __builtin_amdgcn_global_load_lds(
        (const __attribute__((address_space(1))) uint32_t*)g,
        (__attribute__((address_space(3))) uint32_t*)l,
        16, 0, 0);
}

// fp32 [8192,128] -> packed bf16, fp32 row sum-of-squares.
__global__ __launch_bounds__(256) void prep_kernel(const float* __restrict__ out_f,
                                                   const float* __restrict__ tgt_f,
                                                   uint32_t* __restrict__ ab,
                                                   float* __restrict__ xxyy) {
    const float* src = blockIdx.y ? tgt_f : out_f;
    uint32_t* dst = ab + (size_t)blockIdx.y * (BDIM * DDIM / 2);
    float* nrm = xxyy + (size_t)blockIdx.y * BDIM;

    int wid = threadIdx.x >> 6;
    int lane = threadIdx.x & 63;
    int row = blockIdx.x * 4 + wid;

    const float2* s = (const float2*)(src + (size_t)row * DDIM);
    float2 v = s[lane];
    dst[row * (DDIM / 2) + lane] = f2bf1(v.x) | (f2bf1(v.y) << 16);

    float sq = v.x * v.x + v.y * v.y;
    #pragma unroll
    for (int off = 32; off > 0; off >>= 1) sq += __shfl_down(sq, off);
    if (lane == 0) nrm[row] = sq;
}

// 128x128 tile per block; C = A * B^T via mfma 32x32x16 bf16.
// LDS: dense XOR-swizzled layout staged with global_load_lds(16B);
//   slot(r, g) = r*8 + (g ^ (r&7))  (16B slots) -> conflict-free ds_read_b128.
// Grid: 1-D 4096 blocks with XCD-aware swizzle: dispatch is round-robin
// (bid%8 -> XCD), so XCD x owns a 16x32 rectangle of the 64x64 tile grid;
// working set 16 A-tiles + 32 B-tiles = 1.5 MB < 4 MB per-XCD L2.
__global__ __launch_bounds__(256) void dist_kernel(const uint32_t* __restrict__ Ag,
                                                   const uint32_t* __restrict__ Bg,
                                                   const float* __restrict__ xxg,
                                                   const float* __restrict__ yyg,
                                                   float* __restrict__ partials) {
    __shared__ bf16 Al[128 * 64];   // 16 KB per chunk (K=64), reused across chunks
    __shared__ bf16 Bl[128 * 64];
    __shared__ float xxl[128];
    __shared__ float yyl[128];
    __shared__ float wsum[4];

    const int tid = threadIdx.x;
    const int lane = tid & 63;
    const int wid = tid >> 6;
    const int wr = wid >> 1, wc = wid & 1;      // 2x2 wave grid, each wave 64x64

    // XCD-aware swizzle: xcd = bid & 7 (dispatch round-robin), 512 slots/XCD
    // arranged 16 (bx) x 32 (by).
    const int bid = blockIdx.x;
    const int xcd = bid & 7;
    const int slot = bid >> 3;
    const int bx = (xcd & 3) * 16 + (slot & 15);
    const int by = (xcd >> 2) * 32 + (slot >> 4);

    if (tid < 128) xxl[tid] = xxg[bx * 128 + tid];
    else           yyl[tid - 128] = yyg[by * 128 + (tid - 128)];

    // Staging constants (invariant per thread):
    //   slot S = i*256 + tid; r = i*32 + (tid>>3); g = (tid&7) ^ (r&7)
    //   (r&7) == (tid>>3)&7 since i*32 ≡ 0 mod 8 -> g loop-invariant.
    const int rl = tid >> 3;
    const int g  = (tid & 7) ^ (rl & 7);
    const uint8_t* Abase = (const uint8_t*)Ag + ((size_t)bx * 128) * 256  // 256 B/row
                         + rl * 256 + g * 16;
    const uint8_t* Bbase = (const uint8_t*)Bg + ((size_t)by * 128) * 256
                         + rl * 256 + g * 16;
    uint8_t* la = (uint8_t*)Al + tid * 16;
    uint8_t* lb = (uint8_t*)Bl + tid * 16;

    const int lm = lane & 31;                   // fragment row within 32
    const int fh = lane >> 5;                   // k-half

    f32x16 acc[2][2] = {};

    #pragma unroll
    for (int ch = 0; ch < 2; ++ch) {            // two K-chunks of 64
        if (ch) __syncthreads();                // previous compute done
        const uint8_t* ga = Abase + ch * 128;   // chunk = 128 B within the row
        const uint8_t* gb = Bbase + ch * 128;
        #pragma unroll
        for (int i = 0; i < 4; ++i) {           // i advances r by 32 -> +8192 B global
            gload16(ga + i * 8192, la + i * 4096);
            gload16(gb + i * 8192, lb + i * 4096);
        }
        __syncthreads();                        // drains vmcnt -> LDS visible

        #pragma unroll
        for (int k0 = 0; k0 < 64; k0 += 16) {
            const int gf = (k0 >> 3) + fh;      // k-group 0..7
            bf16x8 af[2], bfr[2];
            #pragma unroll
            for (int t = 0; t < 2; ++t) {
                int am = wr * 64 + t * 32 + lm;
                af[t]  = *(const bf16x8*)&Al[(am * 8 + (gf ^ (am & 7))) * 8];
                int bn = wc * 64 + t * 32 + lm;
                bfr[t] = *(const bf16x8*)&Bl[(bn * 8 + (gf ^ (bn & 7))) * 8];
            }
            acc[0][0] = __builtin_amdgcn_mfma_f32_32x32x16_bf16(af[0], bfr[0], acc[0][0], 0, 0, 0);
            acc[0][1] = __builtin_amdgcn_mfma_f32_32x32x16_bf16(af[0], bfr[1], acc[0][1], 0, 0, 0);
            acc[1][0] = __builtin_amdgcn_mfma_f32_32x32x16_bf16(af[1], bfr[0], acc[1][0], 0, 0, 0);
            acc[1][1] = __builtin_amdgcn_mfma_f32_32x32x16_bf16(af[1], bfr[1], acc[1][1], 0, 0, 0);
        }
    }

    // Epilogue: s += sqrt(max(xx+yy-2c, 0)) for every element (fast sqrt).
    float s = 0.0f;
    #pragma unroll
    for (int tr = 0; tr < 2; ++tr) {
        float xv[16];
        #pragma unroll
        for (int r = 0; r < 16; ++r) {
            int ml = wr * 64 + tr * 32 + (r & 3) + 8 * (r >> 2) + 4 * fh;
            xv[r] = xxl[ml];
        }
        #pragma unroll
        for (int tc = 0; tc < 2; ++tc) {
            float yv = yyl[wc * 64 + tc * 32 + lm];
            #pragma unroll
            for (int r = 0; r < 16; ++r) {
                float d2 = fmaf(-2.0f, acc[tr][tc][r], xv[r] + yv);
                s += __builtin_amdgcn_sqrtf(fmaxf(d2, 0.0f));
            }
        }
    }

    // Diagonal correction: only 64 of 4096 blocks, only waves with wr==wc.
    if (bx == by && wr == wc) {
        #pragma unroll
        for (int t = 0; t < 2; ++t) {
            #pragma unroll
            for (int r = 0; r < 16; ++r) {
                int row = (r & 3) + 8 * (r >> 2) + 4 * fh;
                if (row == lm) {
                    int idx = wr * 64 + t * 32 + row;
                    float d2 = fmaf(-2.0f, acc[t][t][r], xxl[idx] + yyl[idx]);
                    s -= 2.0f * __builtin_amdgcn_sqrtf(fmaxf(d2, 0.0f));
                }
            }
        }
    }

    #pragma unroll
    for (int off = 32; off > 0; off >>= 1) s += __shfl_down(s, off);
    if (lane == 0) wsum[wid] = s;
    __syncthreads();
    if (tid == 0) partials[by * 64 + bx] = wsum[0] + wsum[1] + wsum[2] + wsum[3];
}

__global__ __launch_bounds__(256) void reduce_kernel(const float* __restrict__ partials,
                                                     float* __restrict__ out) {
    __shared__ float wsum[4];
    float s = 0.0f;
    for (int i = threadIdx.x; i < 4096; i += 256) s += partials[i];
    #pragma unroll
    for (int off = 32; off > 0; off >>= 1) s += __shfl_down(s, off);
    int lane = threadIdx.x & 63, wid = threadIdx.x >> 6;
    if (lane == 0) wsum[wid] = s;
    __syncthreads();
    if (threadIdx.x == 0)
        out[0] = (wsum[0] + wsum[1] + wsum[2] + wsum[3]) * (0.1f / 8192.0f);
}

extern "C" void kernel_launch(void* const* d_in, const int* in_sizes, int n_in,
                              void* d_out, int out_size, void* d_ws, size_t ws_size,
                              hipStream_t stream) {
    const float* output = (const float*)d_in[0];
    const float* target = (const float*)d_in[1];

    uint8_t* ws = (uint8_t*)d_ws;
    uint32_t* ab      = (uint32_t*)ws;                                   // A bf16 (2MB) + B bf16 (2MB)
    float*    xxyy    = (float*)(ws + 4u * 1024u * 1024u);               // xx (32KB) + yy (32KB)
    float*    partial = (float*)(ws + 4u * 1024u * 1024u + 64u * 1024u); // 4096 floats

    prep_kernel<<<dim3(2048, 2), 256, 0, stream>>>(output, target, ab, xxyy);
    dist_kernel<<<dim3(4096), 256, 0, stream>>>(ab, ab + (BDIM * DDIM / 2),
                                                xxyy, xxyy + BDIM, partial);
    reduce_kernel<<<1, 256, 0, stream>>>(partial, (float*)d_out);
}

// Round 5
// 84.161 us; speedup vs baseline: 1.5093x; 1.1225x over previous
//
#include <hip/hip_runtime.h>
#include <stdint.h>

typedef float f32x16 __attribute__((ext_vector_type(16)));

#define BDIM 8192
// fp8 matrices stored k-major: piece P = s*2+fh (P in [0,16), 8 cols each),
// global byte addr = P*65536 + row*8. One matrix = 1 MB.

__device__ __forceinline__ void gload16(const void* g, void* l) {
    __builtin_amdgcn_global_load_lds(
        (const __attribute__((address_space(1))) uint32_t*)g,
        (__attribute__((address_space(3))) uint32_t*)l,
        16, 0, 0);
}

// fp32 [8192,128] -> fp8 e4m3 in k-major piece layout + fp32 row sum-of-squares.
// grid (512, 2): 16 rows/block. Lane: j = lane&15 (col-group of 8), r = +lane>>4.
__global__ __launch_bounds__(256) void prep_kernel(const float* __restrict__ out_f,
                                                   const float* __restrict__ tgt_f,
                                                   uint8_t* __restrict__ ak,
                                                   float* __restrict__ xxyy) {
    const float* src = blockIdx.y ? tgt_f : out_f;
    uint8_t* dst = ak + (size_t)blockIdx.y * (1u << 20);
    float* nrm = xxyy + (size_t)blockIdx.y * BDIM;

    const int tid = threadIdx.x;
    const int lane = tid & 63;
    const int w = tid >> 6;
    const int j = lane & 15;                       // col-group: cols 8j..8j+7
    const int r = blockIdx.x * 16 + w * 4 + (lane >> 4);

    const float4* s4 = (const float4*)(src + (size_t)r * 128 + j * 8);
    float4 a = s4[0], b = s4[1];

    uint32_t w0 = __builtin_amdgcn_cvt_pk_fp8_f32(a.x, a.y, 0, false);
    w0 = __builtin_amdgcn_cvt_pk_fp8_f32(a.z, a.w, w0, true);
    uint32_t w1 = __builtin_amdgcn_cvt_pk_fp8_f32(b.x, b.y, 0, false);
    w1 = __builtin_amdgcn_cvt_pk_fp8_f32(b.z, b.w, w1, true);
    *(uint2*)(dst + j * 65536 + r * 8) = make_uint2(w0, w1);

    float sq = a.x*a.x + a.y*a.y + a.z*a.z + a.w*a.w
             + b.x*b.x + b.y*b.y + b.z*b.z + b.w*b.w;
    sq += __shfl_xor(sq, 1); sq += __shfl_xor(sq, 2);
    sq += __shfl_xor(sq, 4); sq += __shfl_xor(sq, 8);   // reduce over the 16 j-lanes
    if (j == 0) nrm[r] = sq;
}

// 128x128 tile per block; C = A * B^T via mfma 32x32x16 fp8_fp8 (full K=128
// staged once, single vmcnt drain, 3 barriers total). LDS layout matches the
// k-major global layout: addr = (P*128 + m)*8 -> fragment read is a
// lane-linear ds_read_b64 at base + s*2048 (literal offsets, conflict-free).
__global__ __launch_bounds__(256, 4) void dist_kernel(const uint8_t* __restrict__ Ak,
                                                      const uint8_t* __restrict__ Bk,
                                                      const float* __restrict__ xxg,
                                                      const float* __restrict__ yyg,
                                                      float* __restrict__ partials) {
    __shared__ uint8_t Al[16384];
    __shared__ uint8_t Bl[16384];
    __shared__ float xxl[128];
    __shared__ float yyl[128];
    __shared__ float wsum[4];

    const int tid = threadIdx.x;
    const int lane = tid & 63;
    const int wid = tid >> 6;
    const int wr = wid >> 1, wc = wid & 1;      // 2x2 wave grid, each wave 64x64
    const int bx = blockIdx.x, by = blockIdx.y;

    if (tid < 128) xxl[tid] = xxg[bx * 128 + tid];
    else           yyl[tid - 128] = yyg[by * 128 + (tid - 128)];

    // Stage both tiles (16 KB each), one shot. Slot S = i*256+tid holds
    // piece P = i*4+wid, rows bx*128 + (lane*2 .. +2): 16 contiguous bytes.
    {
        const uint8_t* ga = Ak + wid * 65536 + bx * 1024 + lane * 16;
        const uint8_t* gb = Bk + wid * 65536 + by * 1024 + lane * 16;
        uint8_t* la = Al + tid * 16;
        uint8_t* lb = Bl + tid * 16;
        #pragma unroll
        for (int i = 0; i < 4; ++i) {
            gload16(ga + i * 262144, la + i * 4096);
            gload16(gb + i * 262144, lb + i * 4096);
        }
    }
    __syncthreads();                            // single vmcnt(0) drain

    const int lm = lane & 31;                   // fragment row/col within 32
    const int fh = lane >> 5;                   // k-half
    const uint8_t* abase = Al + fh * 1024 + (wr * 64 + lm) * 8;
    const uint8_t* bbase = Bl + fh * 1024 + (wc * 64 + lm) * 8;

    f32x16 acc[2][2] = {};
    #pragma unroll
    for (int s = 0; s < 8; ++s) {               // K = 8 steps of 16
        long a0 = *(const long*)(abase + s * 2048);
        long a1 = *(const long*)(abase + s * 2048 + 256);   // +32 rows
        long b0 = *(const long*)(bbase + s * 2048);
        long b1 = *(const long*)(bbase + s * 2048 + 256);
        acc[0][0] = __builtin_amdgcn_mfma_f32_32x32x16_fp8_fp8(a0, b0, acc[0][0], 0, 0, 0);
        acc[0][1] = __builtin_amdgcn_mfma_f32_32x32x16_fp8_fp8(a0, b1, acc[0][1], 0, 0, 0);
        acc[1][0] = __builtin_amdgcn_mfma_f32_32x32x16_fp8_fp8(a1, b0, acc[1][0], 0, 0, 0);
        acc[1][1] = __builtin_amdgcn_mfma_f32_32x32x16_fp8_fp8(a1, b1, acc[1][1], 0, 0, 0);
    }

    // Epilogue: s += sqrt(max(xx+yy-2c, 0)), fast sqrt, 2-way split chain.
    float s0 = 0.0f, s1 = 0.0f;
    #pragma unroll
    for (int tr = 0; tr < 2; ++tr) {
        float xv[16];
        #pragma unroll
        for (int r = 0; r < 16; ++r) {
            int ml = wr * 64 + tr * 32 + (r & 3) + 8 * (r >> 2) + 4 * fh;
            xv[r] = xxl[ml];
        }
        #pragma unroll
        for (int tc = 0; tc < 2; ++tc) {
            float yv = yyl[wc * 64 + tc * 32 + lm];
            #pragma unroll
            for (int r = 0; r < 16; ++r) {
                float d2 = fmaf(-2.0f, acc[tr][tc][r], xv[r] + yv);
                float d = __builtin_amdgcn_sqrtf(fmaxf(d2, 0.0f));
                if (r & 1) s1 += d; else s0 += d;
            }
        }
    }
    float s = s0 + s1;

    // Diagonal correction: only 64 of 4096 blocks, only waves with wr==wc.
    if (bx == by && wr == wc) {
        #pragma unroll
        for (int t = 0; t < 2; ++t) {
            #pragma unroll
            for (int r = 0; r < 16; ++r) {
                int row = (r & 3) + 8 * (r >> 2) + 4 * fh;
                if (row == lm) {
                    int idx = wr * 64 + t * 32 + row;
                    float d2 = fmaf(-2.0f, acc[t][t][r], xxl[idx] + yyl[idx]);
                    s -= 2.0f * __builtin_amdgcn_sqrtf(fmaxf(d2, 0.0f));
                }
            }
        }
    }

    #pragma unroll
    for (int off = 32; off > 0; off >>= 1) s += __shfl_down(s, off);
    if (lane == 0) wsum[wid] = s;
    __syncthreads();
    if (tid == 0) partials[by * 64 + bx] = wsum[0] + wsum[1] + wsum[2] + wsum[3];
}

__global__ __launch_bounds__(256) void reduce_kernel(const float* __restrict__ partials,
                                                     float* __restrict__ out) {
    __shared__ float wsum[4];
    float s = 0.0f;
    for (int i = threadIdx.x; i < 4096; i += 256) s += partials[i];
    #pragma unroll
    for (int off = 32; off > 0; off >>= 1) s += __shfl_down(s, off);
    int lane = threadIdx.x & 63, wid = threadIdx.x >> 6;
    if (lane == 0) wsum[wid] = s;
    __syncthreads();
    if (threadIdx.x == 0)
        out[0] = (wsum[0] + wsum[1] + wsum[2] + wsum[3]) * (0.1f / 8192.0f);
}

extern "C" void kernel_launch(void* const* d_in, const int* in_sizes, int n_in,
                              void* d_out, int out_size, void* d_ws, size_t ws_size,
                              hipStream_t stream) {
    const float* output = (const float*)d_in[0];
    const float* target = (const float*)d_in[1];

    uint8_t* ws = (uint8_t*)d_ws;
    uint8_t* ak      = ws;                                    // A fp8 (1MB) + B fp8 (1MB)
    float*   xxyy    = (float*)(ws + 2u * 1024u * 1024u);     // xx (32KB) + yy (32KB)
    float*   partial = (float*)(ws + 2u * 1024u * 1024u + 64u * 1024u); // 4096 floats

    prep_kernel<<<dim3(512, 2), 256, 0, stream>>>(output, target, ak, xxyy);
    dist_kernel<<<dim3(64, 64), 256, 0, stream>>>(ak, ak + (1u << 20),
                                                  xxyy, xxyy + BDIM, partial);
    reduce_kernel<<<1, 256, 0, stream>>>(partial, (float*)d_out);
}